// Round 7
// baseline (123.700 us; speedup 1.0000x reference)
//
#include <hip/hip_runtime.h>

namespace {
constexpr int S = 1024, I = 512, C = 8, H = 8;
constexpr int R = 4;                 // rows per thread
constexpr float LNEPS = 1e-5f;
constexpr float SCALE = 0.35355339059327373f; // 8^-0.5
}

__device__ __forceinline__ float dot8(const float x[8], float4 a, float4 b) {
    float r = x[0] * a.x;
    r += x[1] * a.y; r += x[2] * a.z; r += x[3] * a.w;
    r += x[4] * b.x; r += x[5] * b.y; r += x[6] * b.z; r += x[7] * b.w;
    return r;
}

__device__ __forceinline__ void ln8(float4 a, float4 b, const float gm[8],
                                    const float bt[8], float x[8]) {
    x[0] = a.x; x[1] = a.y; x[2] = a.z; x[3] = a.w;
    x[4] = b.x; x[5] = b.y; x[6] = b.z; x[7] = b.w;
    float mu = 0.f;
#pragma unroll
    for (int c = 0; c < 8; c++) mu += x[c];
    mu *= 0.125f;
    float var = 0.f;
#pragma unroll
    for (int c = 0; c < 8; c++) { float d = x[c] - mu; var += d * d; }
    var *= 0.125f;
    float inv = rsqrtf(var + LNEPS);
#pragma unroll
    for (int c = 0; c < 8; c++) x[c] = (x[c] - mu) * inv * gm[c] + bt[c];
}

// 512 blocks x 256 threads: ONE column per block, 4 rows/thread.
// launch_bounds(256,3) = min 3 BLOCKS/CU (R5 showed CUDA min-blocks
// semantics) -> VGPR cap 170 -> 12 waves/CU (3/SIMD), vs 8 for the
// previous 512-thread/1-block-per-CU shape. Phase 3 is c-outer/h-inner
// so v needs 4 regs not 32; p pre-scaled by 1/den.
__global__ __launch_bounds__(256, 3) void fused(
    const float* __restrict__ m, const float* __restrict__ gamma,
    const float* __restrict__ beta, const float* __restrict__ Wq,
    const float* __restrict__ Wk, const float* __restrict__ Wv,
    const float* __restrict__ Wg, const float* __restrict__ Wo,
    const float* __restrict__ bo, float* __restrict__ out) {
    __shared__ __align__(16) float sWoT[512];   // sWoT[j][c2] = Wo[c2][j]
    __shared__ __align__(16) float swred[4 * 8]; // [wave][c]
    __shared__ __align__(16) float sxbar[8];
    __shared__ __align__(16) float sqk[64];      // [h*8+c2]
    __shared__ __align__(16) float srden[8];     // [h]

    int t = threadIdx.x;
    int w = t >> 6;          // wave id [0,4)
    int i = blockIdx.x;      // this block's column

    // ---- stage transposed Wo (2 elements/thread) ----
#pragma unroll
    for (int k = 0; k < 2; k++) {
        int idx = t + 256 * k;
        int j = idx & 63, c2 = idx >> 6;
        sWoT[j * 8 + c2] = Wo[c2 * 64 + j];
    }

    float gm[8], bt[8];
#pragma unroll
    for (int c = 0; c < 8; c++) { gm[c] = gamma[c]; bt[c] = beta[c]; }

    // ---- phase 1: load m once, LN, LN-sum reduce ----
    const float4* m4 = (const float4*)m;
    float x[R][8];
    float acc[8];
#pragma unroll
    for (int c = 0; c < 8; c++) acc[c] = 0.f;
#pragma unroll
    for (int r = 0; r < R; r++) {
        int row = (t + 256 * r) * I + i;
        ln8(m4[row * 2], m4[row * 2 + 1], gm, bt, x[r]);
#pragma unroll
        for (int c = 0; c < 8; c++) acc[c] += x[r][c];
    }
#pragma unroll
    for (int d = 1; d < 64; d <<= 1)
#pragma unroll
        for (int c = 0; c < 8; c++) acc[c] += __shfl_xor(acc[c], d, 64);
    if ((t & 63) == 0) {
#pragma unroll
        for (int c = 0; c < 8; c++) swred[w * 8 + c] = acc[c];
    }
    __syncthreads();   // S1 (also covers sWoT staging)
    if (t < 8)
        sxbar[t] = swred[t] + swred[8 + t] + swred[16 + t] + swred[24 + t];
    __syncthreads();   // S2
    // qk[h][c2] = SCALE/S * sum_c (xbar . Wq_hc) Wk[c][c2]
    if (t < 64) {
        int h = t >> 3, c2 = t & 7;
        float a = 0.f;
#pragma unroll
        for (int c = 0; c < 8; c++) {
            float qc = 0.f;
#pragma unroll
            for (int c3 = 0; c3 < 8; c3++)
                qc += sxbar[c3] * Wq[(h * 8 + c) * 8 + c3];
            a += qc * Wk[c * 8 + c2];
        }
        sqk[t] = a * (SCALE / 1024.0f);
    }
    __syncthreads();   // S3

    // ---- phase 2: exp logits (cached in p) + denominator reduce ----
    const float4* sqk4 = (const float4*)sqk;
    float p[R][8];
    {
        float e[8];
#pragma unroll
        for (int h = 0; h < 8; h++) {
            float4 q0 = sqk4[h * 2], q1 = sqk4[h * 2 + 1];
            float s = 0.f;
#pragma unroll
            for (int r = 0; r < R; r++) {
                p[r][h] = __expf(dot8(x[r], q0, q1));
                s += p[r][h];
            }
            e[h] = s;
        }
#pragma unroll
        for (int d = 1; d < 64; d <<= 1)
#pragma unroll
            for (int h = 0; h < 8; h++) e[h] += __shfl_xor(e[h], d, 64);
        if ((t & 63) == 0) {
#pragma unroll
            for (int h = 0; h < 8; h++) swred[w * 8 + h] = e[h];
        }
    }
    __syncthreads();   // S4
    if (t < 8)
        srden[t] =
            1.0f / (swred[t] + swred[8 + t] + swred[16 + t] + swred[24 + t]);
    __syncthreads();   // S5

    // pre-scale p by 1/denominator -> srden leaves the hot loop
#pragma unroll
    for (int h = 0; h < 8; h++) {
        float rd = srden[h];
#pragma unroll
        for (int r = 0; r < R; r++) p[r][h] *= rd;
    }

    // ---- phase 3: output, c-outer (v = 4 regs) / h-inner ----
    const float4* Wv4 = (const float4*)Wv;
    const float4* Wg4 = (const float4*)Wg;
    const float4* sWoT4 = (const float4*)sWoT;

    float oacc[R][8];
#pragma unroll
    for (int r = 0; r < R; r++)
#pragma unroll
        for (int c2 = 0; c2 < 8; c2++) oacc[r][c2] = bo[c2];

#pragma unroll 1
    for (int c = 0; c < 8; c++) {
        float4 wv0 = Wv4[c * 2], wv1 = Wv4[c * 2 + 1];
        float vr[R];
#pragma unroll
        for (int r = 0; r < R; r++) vr[r] = dot8(x[r], wv0, wv1);
#pragma unroll 2
        for (int h = 0; h < 8; h++) {
            int hc = h * 8 + c;
            float4 wg0 = Wg4[hc * 2], wg1 = Wg4[hc * 2 + 1];
            float4 wo0 = sWoT4[hc * 2], wo1 = sWoT4[hc * 2 + 1];
            float o_[R];
#pragma unroll
            for (int r = 0; r < R; r++) {
                float z = dot8(x[r], wg0, wg1);
                float gate = __builtin_amdgcn_rcpf(1.0f + __expf(-z));
                o_[r] = gate * p[r][h] * vr[r];
            }
#pragma unroll
            for (int r = 0; r < R; r++) {
                oacc[r][0] += o_[r] * wo0.x; oacc[r][1] += o_[r] * wo0.y;
                oacc[r][2] += o_[r] * wo0.z; oacc[r][3] += o_[r] * wo0.w;
                oacc[r][4] += o_[r] * wo1.x; oacc[r][5] += o_[r] * wo1.y;
                oacc[r][6] += o_[r] * wo1.z; oacc[r][7] += o_[r] * wo1.w;
            }
        }
    }
    float4* out4 = (float4*)out;
#pragma unroll
    for (int r = 0; r < R; r++) {
        int row = (t + 256 * r) * I + i;
        out4[row * 2] = make_float4(oacc[r][0], oacc[r][1], oacc[r][2], oacc[r][3]);
        out4[row * 2 + 1] = make_float4(oacc[r][4], oacc[r][5], oacc[r][6], oacc[r][7]);
    }
}

extern "C" void kernel_launch(void* const* d_in, const int* in_sizes, int n_in,
                              void* d_out, int out_size, void* d_ws, size_t ws_size,
                              hipStream_t stream) {
    const float* m     = (const float*)d_in[0];
    const float* gamma = (const float*)d_in[1];
    const float* beta  = (const float*)d_in[2];
    const float* Wq    = (const float*)d_in[3];
    const float* Wk    = (const float*)d_in[4];
    const float* Wv    = (const float*)d_in[5];
    const float* Wg    = (const float*)d_in[6];
    const float* Wo    = (const float*)d_in[7];
    const float* bo    = (const float*)d_in[8];
    float* out = (float*)d_out;

    fused<<<I, 256, 0, stream>>>(m, gamma, beta, Wq, Wk, Wv, Wg, Wo, bo, out);
}

// Round 8
// 115.236 us; speedup vs baseline: 1.0734x; 1.0734x over previous
//
#include <hip/hip_runtime.h>

namespace {
constexpr int S = 1024, I = 512, C = 8, H = 8;
constexpr int R = 4;                 // rows per thread (per its column)
constexpr float LNEPS = 1e-5f;
constexpr float SCALE = 0.35355339059327373f; // 8^-0.5
}

__device__ __forceinline__ float dot8(const float x[8], float4 a, float4 b) {
    float r = x[0] * a.x;
    r += x[1] * a.y; r += x[2] * a.z; r += x[3] * a.w;
    r += x[4] * b.x; r += x[5] * b.y; r += x[6] * b.z; r += x[7] * b.w;
    return r;
}

__device__ __forceinline__ void ln8(float4 a, float4 b, const float gm[8],
                                    const float bt[8], float x[8]) {
    x[0] = a.x; x[1] = a.y; x[2] = a.z; x[3] = a.w;
    x[4] = b.x; x[5] = b.y; x[6] = b.z; x[7] = b.w;
    float mu = 0.f;
#pragma unroll
    for (int c = 0; c < 8; c++) mu += x[c];
    mu *= 0.125f;
    float var = 0.f;
#pragma unroll
    for (int c = 0; c < 8; c++) { float d = x[c] - mu; var += d * d; }
    var *= 0.125f;
    float inv = rsqrtf(var + LNEPS);
#pragma unroll
    for (int c = 0; c < 8; c++) x[c] = (x[c] - mu) * inv * gm[c] + bt[c];
}

// 256 blocks x 512 threads, 2 columns/block (64B-coalesced lane pairs),
// 4 rows/thread. All reductions block-local.
// __launch_bounds__(512,2): the only empirically-safe capped config
// (R4: fine; R5 (512,4) and R7 (256,3) both produced a 64-VGPR cap).
// Target: <=128 VGPR -> 2 blocks/CU -> 16 waves/CU, zero spills.
// NO register array is indexed by a runtime subscript (rule #20):
// the exp-cache p[][] is gone — a_ is recomputed per h from sqk (LDS).
__global__ __launch_bounds__(512, 2) void fused(
    const float* __restrict__ m, const float* __restrict__ gamma,
    const float* __restrict__ beta, const float* __restrict__ Wq,
    const float* __restrict__ Wk, const float* __restrict__ Wv,
    const float* __restrict__ Wg, const float* __restrict__ Wo,
    const float* __restrict__ bo, float* __restrict__ out) {
    __shared__ __align__(16) float sWoT[512];     // sWoT[j][c2] = Wo[c2][j]
    __shared__ __align__(16) float swred[8 * 16]; // [wave][col*8+c]
    __shared__ __align__(16) float sxbar[16];     // [col][c]
    __shared__ __align__(16) float sqk[128];      // [col][h*8+c2]
    __shared__ __align__(16) float srden[16];     // [col][h]

    int t = threadIdx.x;
    int w = t >> 6;          // wave id [0,8)
    int col = t & 1;         // which of the block's 2 columns
    int si = t >> 1;         // [0,256): s = si + 256*r
    int i = 2 * blockIdx.x + col;

    // ---- stage transposed Wo (1 elem/thread) ----
    {
        int j = t & 63, c2 = t >> 6;
        sWoT[j * 8 + c2] = Wo[c2 * 64 + j];
    }

    float gm[8], bt[8];
#pragma unroll
    for (int c = 0; c < 8; c++) { gm[c] = gamma[c]; bt[c] = beta[c]; }

    // ---- phase 1: load m once, LN, per-thread LN-sum ----
    const float4* m4 = (const float4*)m;
    float x[R][8];
    float acc[8];
#pragma unroll
    for (int c = 0; c < 8; c++) acc[c] = 0.f;
#pragma unroll
    for (int r = 0; r < R; r++) {
        int row = (si + 256 * r) * I + i;
        ln8(m4[row * 2], m4[row * 2 + 1], gm, bt, x[r]);
#pragma unroll
        for (int c = 0; c < 8; c++) acc[c] += x[r][c];
    }
    // parity-preserving wave reduce (keeps col separate)
#pragma unroll
    for (int d = 2; d < 64; d <<= 1)
#pragma unroll
        for (int c = 0; c < 8; c++) acc[c] += __shfl_xor(acc[c], d, 64);
    if ((t & 63) < 2) {
#pragma unroll
        for (int c = 0; c < 8; c++) swred[w * 16 + col * 8 + c] = acc[c];
    }
    __syncthreads();   // S1 (also covers sWoT staging)
    if (t < 16) {      // col = t>>3, c = t&7
        float s = 0.f;
#pragma unroll
        for (int ww = 0; ww < 8; ww++) s += swred[ww * 16 + t];
        sxbar[t] = s;
    }
    __syncthreads();   // S2
    // qk[col][h][c2] = SCALE/S * sum_c (xbar . Wq_hc) Wk[c][c2]
    if (t < 128) {
        int qcol = t >> 6, h = (t >> 3) & 7, c2 = t & 7;
        float xb[8];
#pragma unroll
        for (int c3 = 0; c3 < 8; c3++) xb[c3] = sxbar[qcol * 8 + c3];
        float a = 0.f;
#pragma unroll
        for (int c = 0; c < 8; c++) {
            float qc = 0.f;
#pragma unroll
            for (int c3 = 0; c3 < 8; c3++)
                qc += xb[c3] * Wq[(h * 8 + c) * 8 + c3];
            a += qc * Wk[c * 8 + c2];
        }
        sqk[qcol * 64 + h * 8 + c2] = a * (SCALE / 1024.0f);
    }
    __syncthreads();   // S3

    // ---- phase 2: exp sums (full unroll; no cache) + denominator ----
    const float4* sqk4 = (const float4*)sqk;
    {
        float e[8];
#pragma unroll
        for (int h = 0; h < 8; h++) {
            float4 q0 = sqk4[col * 16 + h * 2], q1 = sqk4[col * 16 + h * 2 + 1];
            float s = 0.f;
#pragma unroll
            for (int r = 0; r < R; r++) s += __expf(dot8(x[r], q0, q1));
            e[h] = s;
        }
#pragma unroll
        for (int d = 2; d < 64; d <<= 1)
#pragma unroll
            for (int h = 0; h < 8; h++) e[h] += __shfl_xor(e[h], d, 64);
        if ((t & 63) < 2) {
#pragma unroll
            for (int h = 0; h < 8; h++) swred[w * 16 + col * 8 + h] = e[h];
        }
    }
    __syncthreads();   // S4
    if (t < 16) {
        float s = 0.f;
#pragma unroll
        for (int ww = 0; ww < 8; ww++) s += swred[ww * 16 + t];
        srden[t] = 1.0f / s;
    }
    __syncthreads();   // S5

    // ---- phase 3: output. v precomputed (static idx); a_ recomputed per h
    //      from sqk (LDS, runtime-h legal). No runtime-indexed reg arrays. ----
    const float4* Wv4 = (const float4*)Wv;
    const float4* Wg4 = (const float4*)Wg;
    const float4* sWoT4 = (const float4*)sWoT;

    float v[R][8];
#pragma unroll
    for (int c = 0; c < 8; c++) {
        float4 w0 = Wv4[c * 2], w1 = Wv4[c * 2 + 1];
#pragma unroll
        for (int r = 0; r < R; r++) v[r][c] = dot8(x[r], w0, w1);
    }

    float oacc[R][8];
#pragma unroll
    for (int r = 0; r < R; r++)
#pragma unroll
        for (int c2 = 0; c2 < 8; c2++) oacc[r][c2] = bo[c2];

#pragma unroll 1
    for (int h = 0; h < 8; h++) {
        float4 q0 = sqk4[col * 16 + h * 2], q1 = sqk4[col * 16 + h * 2 + 1];
        float rd = srden[col * 8 + h];
        float a_[R];
#pragma unroll
        for (int r = 0; r < R; r++)
            a_[r] = __expf(dot8(x[r], q0, q1)) * rd;  // bit-identical to phase 2
#pragma unroll
        for (int c = 0; c < 8; c++) {
            int hc = h * 8 + c;
            float4 wg0 = Wg4[hc * 2], wg1 = Wg4[hc * 2 + 1];
            float o_[R];
#pragma unroll
            for (int r = 0; r < R; r++) {
                float z = dot8(x[r], wg0, wg1);
                float gate = __builtin_amdgcn_rcpf(1.0f + __expf(-z));
                o_[r] = gate * a_[r] * v[r][c];
            }
            float4 wo0 = sWoT4[hc * 2], wo1 = sWoT4[hc * 2 + 1];
#pragma unroll
            for (int r = 0; r < R; r++) {
                oacc[r][0] += o_[r] * wo0.x; oacc[r][1] += o_[r] * wo0.y;
                oacc[r][2] += o_[r] * wo0.z; oacc[r][3] += o_[r] * wo0.w;
                oacc[r][4] += o_[r] * wo1.x; oacc[r][5] += o_[r] * wo1.y;
                oacc[r][6] += o_[r] * wo1.z; oacc[r][7] += o_[r] * wo1.w;
            }
        }
    }
    float4* out4 = (float4*)out;
#pragma unroll
    for (int r = 0; r < R; r++) {
        int row = (si + 256 * r) * I + i;
        out4[row * 2] = make_float4(oacc[r][0], oacc[r][1], oacc[r][2], oacc[r][3]);
        out4[row * 2 + 1] = make_float4(oacc[r][4], oacc[r][5], oacc[r][6], oacc[r][7]);
    }
}

extern "C" void kernel_launch(void* const* d_in, const int* in_sizes, int n_in,
                              void* d_out, int out_size, void* d_ws, size_t ws_size,
                              hipStream_t stream) {
    const float* m     = (const float*)d_in[0];
    const float* gamma = (const float*)d_in[1];
    const float* beta  = (const float*)d_in[2];
    const float* Wq    = (const float*)d_in[3];
    const float* Wk    = (const float*)d_in[4];
    const float* Wv    = (const float*)d_in[5];
    const float* Wg    = (const float*)d_in[6];
    const float* Wo    = (const float*)d_in[7];
    const float* bo    = (const float*)d_in[8];
    float* out = (float*)d_out;

    fused<<<I / 2, 512, 0, stream>>>(m, gamma, beta, Wq, Wk, Wv, Wg, Wo, bo, out);
}

// Round 9
// 113.764 us; speedup vs baseline: 1.0873x; 1.0129x over previous
//
#include <hip/hip_runtime.h>

namespace {
constexpr int S = 1024, I = 512, C = 8, H = 8;
constexpr int R = 2;                 // rows per thread (per its column)
constexpr float LNEPS = 1e-5f;
constexpr float SCALE = 0.35355339059327373f; // 8^-0.5
}

__device__ __forceinline__ float dot8(const float x[8], float4 a, float4 b) {
    float r = x[0] * a.x;
    r += x[1] * a.y; r += x[2] * a.z; r += x[3] * a.w;
    r += x[4] * b.x; r += x[5] * b.y; r += x[6] * b.z; r += x[7] * b.w;
    return r;
}

__device__ __forceinline__ void ln8(float4 a, float4 b, const float gm[8],
                                    const float bt[8], float x[8]) {
    x[0] = a.x; x[1] = a.y; x[2] = a.z; x[3] = a.w;
    x[4] = b.x; x[5] = b.y; x[6] = b.z; x[7] = b.w;
    float mu = 0.f;
#pragma unroll
    for (int c = 0; c < 8; c++) mu += x[c];
    mu *= 0.125f;
    float var = 0.f;
#pragma unroll
    for (int c = 0; c < 8; c++) { float d = x[c] - mu; var += d * d; }
    var *= 0.125f;
    float inv = rsqrtf(var + LNEPS);
#pragma unroll
    for (int c = 0; c < 8; c++) x[c] = (x[c] - mu) * inv * gm[c] + bt[c];
}

// 256 blocks x 1024 threads, 2 columns/block (64B-coalesced lane pairs),
// 2 rows/thread. Block owns all 1024 rows of its 2 columns -> block-local
// reductions. R8 counters showed the 512-thread shape ran 2 waves/SIMD
// with 80% stall cycles; this shape runs 16 waves/CU (4/SIMD) with the
// SAME memory pattern and per-row math. No launch_bounds 2nd arg
// (toolchain mis-caps); 1024-thr block implies a safe 128-VGPR budget,
// live set ~60. No runtime-indexed register arrays (rule #20).
__global__ __launch_bounds__(1024) void fused(
    const float* __restrict__ m, const float* __restrict__ gamma,
    const float* __restrict__ beta, const float* __restrict__ Wq,
    const float* __restrict__ Wk, const float* __restrict__ Wv,
    const float* __restrict__ Wg, const float* __restrict__ Wo,
    const float* __restrict__ bo, float* __restrict__ out) {
    __shared__ __align__(16) float sWoT[512];      // sWoT[j][c2] = Wo[c2][j]
    __shared__ __align__(16) float swred[16 * 16]; // [wave][col*8+c]
    __shared__ __align__(16) float sxbar[16];      // [col][c]
    __shared__ __align__(16) float sqk[128];       // [col][h*8+c2]
    __shared__ __align__(16) float srden[16];      // [col][h]

    int t = threadIdx.x;
    int w = t >> 6;          // wave id [0,16)
    int col = t & 1;         // which of the block's 2 columns
    int si = t >> 1;         // [0,512): s = si + 512*r
    int i = 2 * blockIdx.x + col;

    // ---- stage transposed Wo ----
    if (t < 512) {
        int j = t & 63, c2 = t >> 6;
        sWoT[j * 8 + c2] = Wo[c2 * 64 + j];
    }

    float gm[8], bt[8];
#pragma unroll
    for (int c = 0; c < 8; c++) { gm[c] = gamma[c]; bt[c] = beta[c]; }

    // ---- phase 1: load m once, LN, per-thread LN-sum ----
    const float4* m4 = (const float4*)m;
    float x[R][8];
    float acc[8];
#pragma unroll
    for (int c = 0; c < 8; c++) acc[c] = 0.f;
#pragma unroll
    for (int r = 0; r < R; r++) {
        int row = (si + 512 * r) * I + i;
        ln8(m4[row * 2], m4[row * 2 + 1], gm, bt, x[r]);
#pragma unroll
        for (int c = 0; c < 8; c++) acc[c] += x[r][c];
    }
    // parity-preserving wave reduce (keeps col separate)
#pragma unroll
    for (int d = 2; d < 64; d <<= 1)
#pragma unroll
        for (int c = 0; c < 8; c++) acc[c] += __shfl_xor(acc[c], d, 64);
    if ((t & 63) < 2) {
#pragma unroll
        for (int c = 0; c < 8; c++) swred[w * 16 + col * 8 + c] = acc[c];
    }
    __syncthreads();   // S1 (also covers sWoT staging)
    if (t < 16) {      // col = t>>3, c = t&7
        float s = 0.f;
#pragma unroll
        for (int ww = 0; ww < 16; ww++) s += swred[ww * 16 + t];
        sxbar[t] = s;
    }
    __syncthreads();   // S2
    // qk[col][h][c2] = SCALE/S * sum_c (xbar . Wq_hc) Wk[c][c2]
    if (t < 128) {
        int qcol = t >> 6, h = (t >> 3) & 7, c2 = t & 7;
        float xb[8];
#pragma unroll
        for (int c3 = 0; c3 < 8; c3++) xb[c3] = sxbar[qcol * 8 + c3];
        float a = 0.f;
#pragma unroll
        for (int c = 0; c < 8; c++) {
            float qc = 0.f;
#pragma unroll
            for (int c3 = 0; c3 < 8; c3++)
                qc += xb[c3] * Wq[(h * 8 + c) * 8 + c3];
            a += qc * Wk[c * 8 + c2];
        }
        sqk[qcol * 64 + h * 8 + c2] = a * (SCALE / 1024.0f);
    }
    __syncthreads();   // S3

    // ---- phase 2: exp sums (no cache) + denominator ----
    const float4* sqk4 = (const float4*)sqk;
    {
        float e[8];
#pragma unroll
        for (int h = 0; h < 8; h++) {
            float4 q0 = sqk4[col * 16 + h * 2], q1 = sqk4[col * 16 + h * 2 + 1];
            float s = 0.f;
#pragma unroll
            for (int r = 0; r < R; r++) s += __expf(dot8(x[r], q0, q1));
            e[h] = s;
        }
#pragma unroll
        for (int d = 2; d < 64; d <<= 1)
#pragma unroll
            for (int h = 0; h < 8; h++) e[h] += __shfl_xor(e[h], d, 64);
        if ((t & 63) < 2) {
#pragma unroll
            for (int h = 0; h < 8; h++) swred[w * 16 + col * 8 + h] = e[h];
        }
    }
    __syncthreads();   // S4
    if (t < 16) {
        float s = 0.f;
#pragma unroll
        for (int ww = 0; ww < 16; ww++) s += swred[ww * 16 + t];
        srden[t] = 1.0f / s;
    }
    __syncthreads();   // S5

    // ---- phase 3: output. v precomputed (static idx); a_ recomputed per h
    //      from sqk (LDS, runtime-h legal). ----
    const float4* Wv4 = (const float4*)Wv;
    const float4* Wg4 = (const float4*)Wg;
    const float4* sWoT4 = (const float4*)sWoT;

    float v[R][8];
#pragma unroll
    for (int c = 0; c < 8; c++) {
        float4 w0 = Wv4[c * 2], w1 = Wv4[c * 2 + 1];
#pragma unroll
        for (int r = 0; r < R; r++) v[r][c] = dot8(x[r], w0, w1);
    }

    float oacc[R][8];
#pragma unroll
    for (int r = 0; r < R; r++)
#pragma unroll
        for (int c2 = 0; c2 < 8; c2++) oacc[r][c2] = bo[c2];

#pragma unroll 1
    for (int h = 0; h < 8; h++) {
        float4 q0 = sqk4[col * 16 + h * 2], q1 = sqk4[col * 16 + h * 2 + 1];
        float rd = srden[col * 8 + h];
        float a_[R];
#pragma unroll
        for (int r = 0; r < R; r++)
            a_[r] = __expf(dot8(x[r], q0, q1)) * rd;  // bit-identical to phase 2
#pragma unroll
        for (int c = 0; c < 8; c++) {
            int hc = h * 8 + c;
            float4 wg0 = Wg4[hc * 2], wg1 = Wg4[hc * 2 + 1];
            float o_[R];
#pragma unroll
            for (int r = 0; r < R; r++) {
                float z = dot8(x[r], wg0, wg1);
                float gate = __builtin_amdgcn_rcpf(1.0f + __expf(-z));
                o_[r] = gate * a_[r] * v[r][c];
            }
            float4 wo0 = sWoT4[hc * 2], wo1 = sWoT4[hc * 2 + 1];
#pragma unroll
            for (int r = 0; r < R; r++) {
                oacc[r][0] += o_[r] * wo0.x; oacc[r][1] += o_[r] * wo0.y;
                oacc[r][2] += o_[r] * wo0.z; oacc[r][3] += o_[r] * wo0.w;
                oacc[r][4] += o_[r] * wo1.x; oacc[r][5] += o_[r] * wo1.y;
                oacc[r][6] += o_[r] * wo1.z; oacc[r][7] += o_[r] * wo1.w;
            }
        }
    }
    float4* out4 = (float4*)out;
#pragma unroll
    for (int r = 0; r < R; r++) {
        int row = (si + 512 * r) * I + i;
        out4[row * 2] = make_float4(oacc[r][0], oacc[r][1], oacc[r][2], oacc[r][3]);
        out4[row * 2 + 1] = make_float4(oacc[r][4], oacc[r][5], oacc[r][6], oacc[r][7]);
    }
}

extern "C" void kernel_launch(void* const* d_in, const int* in_sizes, int n_in,
                              void* d_out, int out_size, void* d_ws, size_t ws_size,
                              hipStream_t stream) {
    const float* m     = (const float*)d_in[0];
    const float* gamma = (const float*)d_in[1];
    const float* beta  = (const float*)d_in[2];
    const float* Wq    = (const float*)d_in[3];
    const float* Wk    = (const float*)d_in[4];
    const float* Wv    = (const float*)d_in[5];
    const float* Wg    = (const float*)d_in[6];
    const float* Wo    = (const float*)d_in[7];
    const float* bo    = (const float*)d_in[8];
    float* out = (float*)d_out;

    fused<<<I / 2, 1024, 0, stream>>>(m, gamma, beta, Wq, Wk, Wv, Wg, Wo, bo, out);
}

// Round 10
// 111.295 us; speedup vs baseline: 1.1115x; 1.0222x over previous
//
#include <hip/hip_runtime.h>

namespace {
constexpr int S = 1024, I = 512, C = 8, H = 8;
constexpr int R = 2;                 // rows per thread (per its column)
constexpr float LNEPS = 1e-5f;
constexpr float SCALE = 0.35355339059327373f; // 8^-0.5
}

__device__ __forceinline__ float dot8(const float x[8], float4 a, float4 b) {
    float r = x[0] * a.x;
    r += x[1] * a.y; r += x[2] * a.z; r += x[3] * a.w;
    r += x[4] * b.x; r += x[5] * b.y; r += x[6] * b.z; r += x[7] * b.w;
    return r;
}

__device__ __forceinline__ void ln8(float4 a, float4 b, const float gm[8],
                                    const float bt[8], float x[8]) {
    x[0] = a.x; x[1] = a.y; x[2] = a.z; x[3] = a.w;
    x[4] = b.x; x[5] = b.y; x[6] = b.z; x[7] = b.w;
    float mu = 0.f;
#pragma unroll
    for (int c = 0; c < 8; c++) mu += x[c];
    mu *= 0.125f;
    float var = 0.f;
#pragma unroll
    for (int c = 0; c < 8; c++) { float d = x[c] - mu; var += d * d; }
    var *= 0.125f;
    float inv = rsqrtf(var + LNEPS);
#pragma unroll
    for (int c = 0; c < 8; c++) x[c] = (x[c] - mu) * inv * gm[c] + bt[c];
}

// 256 blocks x 1024 threads, 2 columns/block, 2 rows/thread.
// Grid == CU count -> ALWAYS 1 block/CU = 16 waves/CU (4/SIMD), for any
// VGPR count <= 512. Therefore: spend registers on ILP. Phase 3 is FULLY
// unrolled (static h,c) and the exp-cache p[2][8] is back (static idx,
// rule #20-safe). No launch_bounds 2nd arg (toolchain mis-caps).
__global__ __launch_bounds__(1024) void fused(
    const float* __restrict__ m, const float* __restrict__ gamma,
    const float* __restrict__ beta, const float* __restrict__ Wq,
    const float* __restrict__ Wk, const float* __restrict__ Wv,
    const float* __restrict__ Wg, const float* __restrict__ Wo,
    const float* __restrict__ bo, float* __restrict__ out) {
    __shared__ __align__(16) float sWoT[512];      // sWoT[j][c2] = Wo[c2][j]
    __shared__ __align__(16) float swred[16 * 16]; // [wave][col*8+c]
    __shared__ __align__(16) float sxbar[16];      // [col][c]
    __shared__ __align__(16) float sqk[128];       // [col][h*8+c2]
    __shared__ __align__(16) float srden[16];      // [col][h]

    int t = threadIdx.x;
    int w = t >> 6;          // wave id [0,16)
    int col = t & 1;         // which of the block's 2 columns
    int si = t >> 1;         // [0,512): s = si + 512*r
    int i = 2 * blockIdx.x + col;

    // ---- stage transposed Wo ----
    if (t < 512) {
        int j = t & 63, c2 = t >> 6;
        sWoT[j * 8 + c2] = Wo[c2 * 64 + j];
    }

    float gm[8], bt[8];
#pragma unroll
    for (int c = 0; c < 8; c++) { gm[c] = gamma[c]; bt[c] = beta[c]; }

    // ---- phase 1: load m once, LN, per-thread LN-sum ----
    const float4* m4 = (const float4*)m;
    float x[R][8];
    float acc[8];
#pragma unroll
    for (int c = 0; c < 8; c++) acc[c] = 0.f;
#pragma unroll
    for (int r = 0; r < R; r++) {
        int row = (si + 512 * r) * I + i;
        ln8(m4[row * 2], m4[row * 2 + 1], gm, bt, x[r]);
#pragma unroll
        for (int c = 0; c < 8; c++) acc[c] += x[r][c];
    }
    // parity-preserving wave reduce (keeps col separate)
#pragma unroll
    for (int d = 2; d < 64; d <<= 1)
#pragma unroll
        for (int c = 0; c < 8; c++) acc[c] += __shfl_xor(acc[c], d, 64);
    if ((t & 63) < 2) {
#pragma unroll
        for (int c = 0; c < 8; c++) swred[w * 16 + col * 8 + c] = acc[c];
    }
    __syncthreads();   // S1 (also covers sWoT staging)
    if (t < 16) {      // col = t>>3, c = t&7
        float s = 0.f;
#pragma unroll
        for (int ww = 0; ww < 16; ww++) s += swred[ww * 16 + t];
        sxbar[t] = s;
    }
    __syncthreads();   // S2
    // qk[col][h][c2] = SCALE/S * sum_c (xbar . Wq_hc) Wk[c][c2]
    if (t < 128) {
        int qcol = t >> 6, h = (t >> 3) & 7, c2 = t & 7;
        float xb[8];
#pragma unroll
        for (int c3 = 0; c3 < 8; c3++) xb[c3] = sxbar[qcol * 8 + c3];
        float a = 0.f;
#pragma unroll
        for (int c = 0; c < 8; c++) {
            float qc = 0.f;
#pragma unroll
            for (int c3 = 0; c3 < 8; c3++)
                qc += xb[c3] * Wq[(h * 8 + c) * 8 + c3];
            a += qc * Wk[c * 8 + c2];
        }
        sqk[qcol * 64 + h * 8 + c2] = a * (SCALE / 1024.0f);
    }
    __syncthreads();   // S3

    // ---- phase 2: exp logits cached in p (static idx) + denominator ----
    const float4* sqk4 = (const float4*)sqk;
    float p[R][8];
    {
        float e[8];
#pragma unroll
        for (int h = 0; h < 8; h++) {
            float4 q0 = sqk4[col * 16 + h * 2], q1 = sqk4[col * 16 + h * 2 + 1];
            float s = 0.f;
#pragma unroll
            for (int r = 0; r < R; r++) {
                p[r][h] = __expf(dot8(x[r], q0, q1));
                s += p[r][h];
            }
            e[h] = s;
        }
#pragma unroll
        for (int d = 2; d < 64; d <<= 1)
#pragma unroll
            for (int h = 0; h < 8; h++) e[h] += __shfl_xor(e[h], d, 64);
        if ((t & 63) < 2) {
#pragma unroll
            for (int h = 0; h < 8; h++) swred[w * 16 + col * 8 + h] = e[h];
        }
    }
    __syncthreads();   // S4
    if (t < 16) {
        float s = 0.f;
#pragma unroll
        for (int ww = 0; ww < 16; ww++) s += swred[ww * 16 + t];
        srden[t] = 1.0f / s;
    }
    __syncthreads();   // S5

    // pre-scale p by 1/denominator (LDS read, static p idx)
#pragma unroll
    for (int h = 0; h < 8; h++) {
        float rd = srden[col * 8 + h];
#pragma unroll
        for (int r = 0; r < R; r++) p[r][h] *= rd;
    }

    // ---- phase 3: FULLY unrolled output contraction ----
    const float4* Wv4 = (const float4*)Wv;
    const float4* Wg4 = (const float4*)Wg;
    const float4* sWoT4 = (const float4*)sWoT;

    float oacc[R][8];
#pragma unroll
    for (int r = 0; r < R; r++)
#pragma unroll
        for (int c2 = 0; c2 < 8; c2++) oacc[r][c2] = bo[c2];

#pragma unroll
    for (int c = 0; c < 8; c++) {
        float4 wv0 = Wv4[c * 2], wv1 = Wv4[c * 2 + 1];
        float vr[R];
#pragma unroll
        for (int r = 0; r < R; r++) vr[r] = dot8(x[r], wv0, wv1);
#pragma unroll
        for (int h = 0; h < 8; h++) {
            int hc = h * 8 + c;
            float4 wg0 = Wg4[hc * 2], wg1 = Wg4[hc * 2 + 1];
            float4 wo0 = sWoT4[hc * 2], wo1 = sWoT4[hc * 2 + 1];
            float o_[R];
#pragma unroll
            for (int r = 0; r < R; r++) {
                float z = dot8(x[r], wg0, wg1);
                float gate = __builtin_amdgcn_rcpf(1.0f + __expf(-z));
                o_[r] = gate * p[r][h] * vr[r];
            }
#pragma unroll
            for (int r = 0; r < R; r++) {
                oacc[r][0] += o_[r] * wo0.x; oacc[r][1] += o_[r] * wo0.y;
                oacc[r][2] += o_[r] * wo0.z; oacc[r][3] += o_[r] * wo0.w;
                oacc[r][4] += o_[r] * wo1.x; oacc[r][5] += o_[r] * wo1.y;
                oacc[r][6] += o_[r] * wo1.z; oacc[r][7] += o_[r] * wo1.w;
            }
        }
    }
    float4* out4 = (float4*)out;
#pragma unroll
    for (int r = 0; r < R; r++) {
        int row = (si + 512 * r) * I + i;
        out4[row * 2] = make_float4(oacc[r][0], oacc[r][1], oacc[r][2], oacc[r][3]);
        out4[row * 2 + 1] = make_float4(oacc[r][4], oacc[r][5], oacc[r][6], oacc[r][7]);
    }
}

extern "C" void kernel_launch(void* const* d_in, const int* in_sizes, int n_in,
                              void* d_out, int out_size, void* d_ws, size_t ws_size,
                              hipStream_t stream) {
    const float* m     = (const float*)d_in[0];
    const float* gamma = (const float*)d_in[1];
    const float* beta  = (const float*)d_in[2];
    const float* Wq    = (const float*)d_in[3];
    const float* Wk    = (const float*)d_in[4];
    const float* Wv    = (const float*)d_in[5];
    const float* Wg    = (const float*)d_in[6];
    const float* Wo    = (const float*)d_in[7];
    const float* bo    = (const float*)d_in[8];
    float* out = (float*)d_out;

    fused<<<I / 2, 1024, 0, stream>>>(m, gamma, beta, Wq, Wk, Wv, Wg, Wo, bo, out);
}